// Round 1
// baseline (357.154 us; speedup 1.0000x reference)
//
#include <hip/hip_runtime.h>
#include <math.h>

// ---------------------------------------------------------------------------
// YOLO loss, forward only.
// Inputs (setup_inputs order):
//   d_in[0] l_prediction (32,3,13,13,85) f32
//   d_in[1] m_prediction (32,3,26,26,85) f32
//   d_in[2] s_prediction (32,3,52,52,85) f32
//   d_in[3] targets      (32,50,5)       f32
// Output: 1 float scalar.
//
// Structure: only the conf channel is needed at every cell; the full 85
// channels are needed only at masked (target-hit) cells. So: a prep pass
// digests the 4800 (scale,b,n) targets into packed keys+payload in d_ws,
// then per-scale loss kernels scan 50 keys per image from LDS per cell.
// ---------------------------------------------------------------------------

__constant__ float c_anch[9][2] = {
    {10.f, 13.f},  {16.f, 30.f},   {33.f, 23.f},
    {30.f, 61.f},  {62.f, 45.f},   {59.f, 119.f},
    {116.f, 90.f}, {156.f, 198.f}, {373.f, 326.f}};

__device__ __forceinline__ float softplusf(float x) {
  // logaddexp(0, x), numerically stable
  return fmaxf(x, 0.f) + log1pf(expf(-fabsf(x)));
}
__device__ __forceinline__ float sigmoidf(float x) {
  return 1.f / (1.f + expf(-x));
}

// Exact replication of _bbox_ciou (forward; alpha's stop_gradient is moot).
__device__ __forceinline__ float ciou_f(float px, float py, float pw, float ph,
                                        float gx, float gy, float gw, float gh) {
  float p_x1 = px - pw * 0.5f, p_x2 = px + pw * 0.5f;
  float p_y1 = py - ph * 0.5f, p_y2 = py + ph * 0.5f;
  float g_x1 = gx - gw * 0.5f, g_x2 = gx + gw * 0.5f;
  float g_y1 = gy - gh * 0.5f, g_y2 = gy + gh * 0.5f;
  float iw = fmaxf(fminf(p_x2, g_x2) - fmaxf(p_x1, g_x1), 0.f);
  float ih = fmaxf(fminf(p_y2, g_y2) - fmaxf(p_y1, g_y1), 0.f);
  float inter = iw * ih;
  float a1 = pw * ph, a2 = gw * gh;
  float iou = inter / (a1 + a2 - inter + 1e-6f);
  float dx = gx - px, dy = gy - py;
  float d2 = dx * dx + dy * dy;
  float cw = fmaxf(p_x2, g_x2) - fminf(p_x1, g_x1);
  float ch = fmaxf(p_y2, g_y2) - fminf(p_y1, g_y1);
  float c2 = cw * cw + ch * ch + 1e-6f;
  float dv = atanf(pw / (ph + 1e-6f)) - atanf(gw / (gh + 1e-6f));
  float v = 0.4052847346f * dv * dv;  // 4/pi^2
  float alpha = v / (1.f - iou + v + 1e-6f);
  return iou - d2 / c2 - alpha * v;
}

// One thread per (scale, b, n) target: 3*32*50 = 4800.
// key = gi | gj<<6 | best_n<<12 | ignore_bits<<14 | cls<<17
// payload = {gx, gy, gw, gh, bls}   (grid units, matching reference quirk:
// anchors compared in fraction-of-416 units while gwh is in grid units)
__global__ void prep_kernel(const float* __restrict__ targets,
                            int* __restrict__ keys, float* __restrict__ pay,
                            float* __restrict__ out) {
  int id = blockIdx.x * blockDim.x + threadIdx.x;
  if (id == 0) out[0] = 0.f;  // graph-safe output re-init (stream-ordered)
  if (id >= 4800) return;
  int s = id / 1600;
  int r = id - s * 1600;
  int b = r / 50;
  int n = r - b * 50;
  const float* t = targets + (b * 50 + n) * 5;
  float cls = t[0], cx = t[1], cy = t[2], w = t[3], h = t[4];
  float Wf = (float)(13 << s);
  float gx = cx * Wf, gy = cy * Wf, gw = w * Wf, gh = h * Wf;
  float areag = gw * gh;
  float best = -1.f;
  int bn = 0, ign = 0;
  for (int k = 0; k < 3; ++k) {
    float aw = c_anch[(2 - s) * 3 + k][0] * (1.f / 416.f);
    float ah = c_anch[(2 - s) * 3 + k][1] * (1.f / 416.f);
    float inter = fminf(gw, aw) * fminf(gh, ah);
    float iou = inter / (areag + aw * ah - inter + 1e-6f);
    if (iou > best) { best = iou; bn = k; }  // first-max tie-break == argmax
    if (iou > 0.5f) ign |= (1 << k);
  }
  int gi = (int)floorf(gx);
  int gj = (int)floorf(gy);
  keys[id] = gi | (gj << 6) | (bn << 12) | (ign << 14) | (((int)cls) << 17);
  float* p = pay + id * 5;
  p[0] = gx; p[1] = gy; p[2] = gw; p[3] = gh; p[4] = 2.f - w * h;
}

template <int S>
__global__ __launch_bounds__(256) void loss_kernel(
    const float* __restrict__ pred, const int* __restrict__ keys,
    const float* __restrict__ pay, float* __restrict__ out) {
  constexpr int W = 13 << S;
  constexpr int HW = W * W;
  constexpr int CELLS = 3 * HW;
  constexpr float BAL = (S == 0) ? 0.4f : ((S == 1) ? 1.0f : 4.0f);
  const int b = blockIdx.y;

  __shared__ int skey[50];
  __shared__ float spay[50][5];
  __shared__ float wsum[4];
  if (threadIdx.x < 50) {
    int idx = (S * 32 + b) * 50 + threadIdx.x;
    skey[threadIdx.x] = keys[idx];
#pragma unroll
    for (int q = 0; q < 5; ++q) spay[threadIdx.x][q] = pay[idx * 5 + q];
  }
  __syncthreads();

  int cell = blockIdx.x * 256 + threadIdx.x;
  float local = 0.f;
  if (cell < CELLS) {
    int a = cell / HW;          // constant divisor -> magic mul
    int rem = cell - a * HW;
    int j = rem / W;
    int i = rem - j * W;
    int probe = i | (j << 6);
    int m = -1;
    bool ign = false;
    for (int n = 0; n < 50; ++n) {  // LDS broadcast reads: conflict-free
      int k = skey[n];
      if ((k & 0xFFF) == probe) {
        if (((k >> 12) & 3) == a) m = n;          // last write wins (scatter)
        ign = ign || (((k >> (14 + a)) & 1) != 0);
      }
    }
    const float* pc = pred + (size_t)((b * 3 + a) * HW + rem) * 85;
    float conf = pc[4];
    if (m >= 0) {
      // obj conf (mask==1 implies noobj==0)
      local += 5.f * BAL * (softplusf(conf) - conf);
      // box CIoU
      float aw = c_anch[(2 - S) * 3 + a][0] * (1.f / 416.f);
      float ah = c_anch[(2 - S) * 3 + a][1] * (1.f / 416.f);
      float px = sigmoidf(pc[0]) + (float)i;
      float py = sigmoidf(pc[1]) + (float)j;
      float pw = expf(pc[2]) * aw;
      float ph = expf(pc[3]) * ah;
      float ci = ciou_f(px, py, pw, ph, spay[m][0], spay[m][1], spay[m][2],
                        spay[m][3]);
      local += 0.05f * (1.f - ci) * spay[m][4];
      // class BCE: sum softplus(p_c) - p_cls   (CLS_RATIO == 1)
      int cls = (skey[m] >> 17) & 0x7F;
      float cs = 0.f;
      for (int c = 0; c < 80; ++c) cs += softplusf(pc[5 + c]);
      cs -= pc[5 + cls];
      local += cs;
    } else if (!ign) {
      local += 5.f * BAL * softplusf(conf);  // noobj conf
    }
  }

  // wave (64) shuffle reduce, then 4-wave LDS reduce, one atomic per block
#pragma unroll
  for (int off = 32; off > 0; off >>= 1) local += __shfl_down(local, off, 64);
  int lane = threadIdx.x & 63, wid = threadIdx.x >> 6;
  if (lane == 0) wsum[wid] = local;
  __syncthreads();
  if (threadIdx.x == 0) atomicAdd(out, wsum[0] + wsum[1] + wsum[2] + wsum[3]);
}

extern "C" void kernel_launch(void* const* d_in, const int* in_sizes, int n_in,
                              void* d_out, int out_size, void* d_ws,
                              size_t ws_size, hipStream_t stream) {
  const float* l = (const float*)d_in[0];
  const float* m = (const float*)d_in[1];
  const float* s = (const float*)d_in[2];
  const float* tg = (const float*)d_in[3];
  float* out = (float*)d_out;
  int* keys = (int*)d_ws;                                   // 4800 ints
  float* pay = (float*)((char*)d_ws + 4800 * sizeof(int));  // 4800*5 floats

  hipLaunchKernelGGL(prep_kernel, dim3(19), dim3(256), 0, stream, tg, keys,
                     pay, out);
  // CELLS: 507 -> 2 blocks, 2028 -> 8, 8112 -> 32 (x 32 images)
  hipLaunchKernelGGL((loss_kernel<0>), dim3(2, 32), dim3(256), 0, stream, l,
                     keys, pay, out);
  hipLaunchKernelGGL((loss_kernel<1>), dim3(8, 32), dim3(256), 0, stream, m,
                     keys, pay, out);
  hipLaunchKernelGGL((loss_kernel<2>), dim3(32, 32), dim3(256), 0, stream, s,
                     keys, pay, out);
}

// Round 2
// 157.498 us; speedup vs baseline: 2.2677x; 2.2677x over previous
//
#include <hip/hip_runtime.h>
#include <math.h>

// ---------------------------------------------------------------------------
// YOLO loss, forward only — fused single-pass version.
//   d_in[0] l_prediction (32,3,13,13,85) f32
//   d_in[1] m_prediction (32,3,26,26,85) f32
//   d_in[2] s_prediction (32,3,52,52,85) f32
//   d_in[3] targets      (32,50,5)       f32
// Output: 1 float scalar.
//
// Kernel 1 (grid 42x32): per block, inline-prep the image's 150 (scale,n)
// target keys into LDS, then each thread handles one flat cell (all scales),
// scanning 50 keys for mask/ignore, reading only the conf channel; masked
// cells additionally do CIoU + 80-class BCE with fast transcendentals.
// Per-block partial sums go to d_ws (no atomics). Kernel 2 reduces 1344
// partials -> out[0].
// ---------------------------------------------------------------------------

__constant__ float c_anch[9][2] = {
    {10.f, 13.f},  {16.f, 30.f},   {33.f, 23.f},
    {30.f, 61.f},  {62.f, 45.f},   {59.f, 119.f},
    {116.f, 90.f}, {156.f, 198.f}, {373.f, 326.f}};

__device__ __forceinline__ float sp_fast(float x) {
  // softplus = logaddexp(0,x), stable; fast HW transcendentals (v_exp/v_log)
  return fmaxf(x, 0.f) + __logf(1.f + __expf(-fabsf(x)));
}
__device__ __forceinline__ float sigmoid_fast(float x) {
  return 1.f / (1.f + __expf(-x));
}

__device__ __forceinline__ float ciou_f(float px, float py, float pw, float ph,
                                        float gx, float gy, float gw, float gh) {
  float p_x1 = px - pw * 0.5f, p_x2 = px + pw * 0.5f;
  float p_y1 = py - ph * 0.5f, p_y2 = py + ph * 0.5f;
  float g_x1 = gx - gw * 0.5f, g_x2 = gx + gw * 0.5f;
  float g_y1 = gy - gh * 0.5f, g_y2 = gy + gh * 0.5f;
  float iw = fmaxf(fminf(p_x2, g_x2) - fmaxf(p_x1, g_x1), 0.f);
  float ih = fmaxf(fminf(p_y2, g_y2) - fmaxf(p_y1, g_y1), 0.f);
  float inter = iw * ih;
  float a1 = pw * ph, a2 = gw * gh;
  float iou = inter / (a1 + a2 - inter + 1e-6f);
  float dx = gx - px, dy = gy - py;
  float d2 = dx * dx + dy * dy;
  float cw = fmaxf(p_x2, g_x2) - fminf(p_x1, g_x1);
  float ch = fmaxf(p_y2, g_y2) - fminf(p_y1, g_y1);
  float c2 = cw * cw + ch * ch + 1e-6f;
  float dv = atanf(pw / (ph + 1e-6f)) - atanf(gw / (gh + 1e-6f));
  float v = 0.4052847346f * dv * dv;  // 4/pi^2
  float alpha = v / (1.f - iou + v + 1e-6f);
  return iou - d2 / c2 - alpha * v;
}

// cells per image: s0 507, s1 2028, s2 8112 => 10647 total; 42 blocks x 256
__global__ __launch_bounds__(256) void yolo_fused(
    const float* __restrict__ predL, const float* __restrict__ predM,
    const float* __restrict__ predS, const float* __restrict__ targets,
    float* __restrict__ partial) {
  __shared__ int skey[150];
  __shared__ float spay[150][5];
  __shared__ float wsum[4];
  const int b = blockIdx.y;
  const int t = threadIdx.x;

  // ---- inline prep: 150 (scale,n) target digests for this image ----
  if (t < 150) {
    int s = t / 50;
    int n = t - s * 50;
    const float* tg = targets + (b * 50 + n) * 5;
    float cls = tg[0], cx = tg[1], cy = tg[2], w = tg[3], h = tg[4];
    float Wf = (float)(13 << s);
    float gx = cx * Wf, gy = cy * Wf, gw = w * Wf, gh = h * Wf;
    float areag = gw * gh;
    float best = -1.f;
    int bn = 0, ign = 0;
    for (int k = 0; k < 3; ++k) {
      float aw = c_anch[(2 - s) * 3 + k][0] * (1.f / 416.f);
      float ah = c_anch[(2 - s) * 3 + k][1] * (1.f / 416.f);
      float inter = fminf(gw, aw) * fminf(gh, ah);
      float iou = inter / (areag + aw * ah - inter + 1e-6f);
      if (iou > best) { best = iou; bn = k; }  // first-max == jnp.argmax
      if (iou > 0.5f) ign |= (1 << k);
    }
    int gi = (int)floorf(gx);
    int gj = (int)floorf(gy);
    skey[t] = gi | (gj << 6) | (bn << 12) | (ign << 14) | (((int)cls) << 17);
    spay[t][0] = gx; spay[t][1] = gy; spay[t][2] = gw; spay[t][3] = gh;
    spay[t][4] = 2.f - w * h;
  }
  __syncthreads();

  int cell = blockIdx.x * 256 + t;
  float local = 0.f;
  if (cell < 10647) {
    int s, c;
    const float* pred;
    if (cell < 507)        { s = 0; c = cell;        pred = predL; }
    else if (cell < 2535)  { s = 1; c = cell - 507;  pred = predM; }
    else                   { s = 2; c = cell - 2535; pred = predS; }
    const int W = 13 << s;
    const int HW = W * W;                // = 169 << (2s)
    int a = (c >> (2 * s)) / 169;        // == c / HW (nested floor-div valid)
    int rem = c - a * HW;
    int j = (rem >> s) / 13;             // == rem / W
    int i = rem - j * W;
    const float* pc = pred + (size_t)((b * 3 + a) * HW + rem) * 85;
    float conf = pc[4];                  // issued before the LDS scan

    int probe = i | (j << 6);
    int m = -1;
    bool ign = false;
    const int base = s * 50;
    for (int n = 0; n < 50; ++n) {       // LDS broadcast reads
      int k = skey[base + n];
      if ((k & 0xFFF) == probe) {
        if (((k >> 12) & 3) == a) m = base + n;  // last write wins (scatter)
        ign = ign || (((k >> (14 + a)) & 1) != 0);
      }
    }
    float BAL = (s == 0) ? 0.4f : ((s == 1) ? 1.0f : 4.0f);
    if (m >= 0) {
      // obj conf (mask implies noobj==0); OBJ_RATIO == 5
      local += 5.f * BAL * (sp_fast(conf) - conf);
      // box CIoU
      float aw = c_anch[(2 - s) * 3 + a][0] * (1.f / 416.f);
      float ah = c_anch[(2 - s) * 3 + a][1] * (1.f / 416.f);
      float px = sigmoid_fast(pc[0]) + (float)i;
      float py = sigmoid_fast(pc[1]) + (float)j;
      float pw = __expf(pc[2]) * aw;
      float ph = __expf(pc[3]) * ah;
      float ci = ciou_f(px, py, pw, ph, spay[m][0], spay[m][1], spay[m][2],
                        spay[m][3]);
      local += 0.05f * (1.f - ci) * spay[m][4];
      // class BCE: sum_c softplus(p_c) - p_cls   (CLS_RATIO == 1)
      int clsi = (skey[m] >> 17) & 0x7F;
      float cs = 0.f;
#pragma unroll 4
      for (int cch = 0; cch < 80; ++cch) cs += sp_fast(pc[5 + cch]);
      cs -= pc[5 + clsi];
      local += cs;
    } else if (!ign) {
      local += 5.f * BAL * sp_fast(conf);  // noobj conf
    }
  }

  // wave(64) shuffle reduce, then 4-wave LDS reduce, one store per block
#pragma unroll
  for (int off = 32; off > 0; off >>= 1) local += __shfl_down(local, off, 64);
  int lane = t & 63, wid = t >> 6;
  if (lane == 0) wsum[wid] = local;
  __syncthreads();
  if (t == 0)
    partial[b * gridDim.x + blockIdx.x] = wsum[0] + wsum[1] + wsum[2] + wsum[3];
}

__global__ __launch_bounds__(256) void reduce_kernel(
    const float* __restrict__ partial, float* __restrict__ out, int n) {
  __shared__ float wsum[4];
  float v = 0.f;
  for (int idx = threadIdx.x; idx < n; idx += 256) v += partial[idx];
#pragma unroll
  for (int off = 32; off > 0; off >>= 1) v += __shfl_down(v, off, 64);
  int lane = threadIdx.x & 63, wid = threadIdx.x >> 6;
  if (lane == 0) wsum[wid] = v;
  __syncthreads();
  if (threadIdx.x == 0) out[0] = wsum[0] + wsum[1] + wsum[2] + wsum[3];
}

extern "C" void kernel_launch(void* const* d_in, const int* in_sizes, int n_in,
                              void* d_out, int out_size, void* d_ws,
                              size_t ws_size, hipStream_t stream) {
  const float* l = (const float*)d_in[0];
  const float* m = (const float*)d_in[1];
  const float* s = (const float*)d_in[2];
  const float* tg = (const float*)d_in[3];
  float* out = (float*)d_out;
  float* partial = (float*)d_ws;  // 42*32 = 1344 floats

  hipLaunchKernelGGL(yolo_fused, dim3(42, 32), dim3(256), 0, stream, l, m, s,
                     tg, partial);
  hipLaunchKernelGGL(reduce_kernel, dim3(1), dim3(256), 0, stream, partial,
                     out, 42 * 32);
}